// Round 1
// baseline (1207.077 us; speedup 1.0000x reference)
//
#include <hip/hip_runtime.h>

// Balanced sinkhorn: 10 outer SGD steps on w[256]; each step = forward sinkhorn
// (3 iters, diagonal-rescale form) + hand-derived reverse-mode grad wrt w.
// All heavy passes stream features[16384,256] f32 and rebuild E = exp(f/0.05)
// on the fly as per-row-scaled f32 exp2 (scale cancels everywhere except u0).

namespace {

constexpr int BATCH = 16384;   // B
constexpr int KDIM  = 256;     // K
constexpr float L2E20 = 28.853900817779268f;  // 20 * log2(e)

__device__ __forceinline__ double fast_exp_d(double x) {
  const double LOG2E  = 1.4426950408889634074;
  const double LN2_HI = 6.93147180369123816490e-01;
  const double LN2_LO = 1.90821492927058770002e-10;
  double n = rint(x * LOG2E);
  double t = fma(-n, LN2_HI, x);
  t = fma(-n, LN2_LO, t);
  double p = 2.4801587301587302e-05;          // 1/8!
  p = fma(p, t, 1.9841269841269841e-04);      // 1/7!
  p = fma(p, t, 1.3888888888888889e-03);      // 1/6!
  p = fma(p, t, 8.3333333333333333e-03);      // 1/5!
  p = fma(p, t, 4.1666666666666664e-02);      // 1/4!
  p = fma(p, t, 1.6666666666666666e-01);      // 1/3!
  p = fma(p, t, 0.5);
  p = fma(p, t, 1.0);
  p = fma(p, t, 1.0);
  long long ni = (long long)n;
  double s = __longlong_as_double((unsigned long long)(ni + 1023LL) << 52);
  return p * s;
}

__device__ __forceinline__ double wave_sum(double v) {
#pragma unroll
  for (int o = 32; o > 0; o >>= 1) v += __shfl_down(v, o);
  return v;
}

__device__ __forceinline__ double block_sum(double v, double* sred, int t) {
  __syncthreads();
  sred[t] = v;
  __syncthreads();
#pragma unroll
  for (int s = 128; s > 0; s >>= 1) {
    if (t < s) sred[t] += sred[t + s];
    __syncthreads();
  }
  double r = sred[0];
  __syncthreads();
  return r;
}

__device__ __forceinline__ double block_max(double v, double* sred, int t) {
  __syncthreads();
  sred[t] = v;
  __syncthreads();
#pragma unroll
  for (int s = 128; s > 0; s >>= 1) {
    if (t < s) sred[t] = fmax(sred[t], sred[t + s]);
    __syncthreads();
  }
  double r = sred[0];
  __syncthreads();
  return r;
}

}  // namespace

// ---------------------------------------------------------------------------
// Row max M[b] = max_k features[b,k]; Sb[b] = exp(20*M[b]) (f64 scale for u0).
__global__ __launch_bounds__(256) void kM(const float* __restrict__ feat,
                                          float* __restrict__ Mrow,
                                          double* __restrict__ Sb) {
  int t = threadIdx.x, wv = t >> 6, lane = t & 63;
  int b0 = blockIdx.x * 64;
  for (int r = wv; r < 64; r += 4) {
    int b = b0 + r;
    float4 f4 = reinterpret_cast<const float4*>(feat + (size_t)b * KDIM)[lane];
    float m = fmaxf(fmaxf(f4.x, f4.y), fmaxf(f4.z, f4.w));
#pragma unroll
    for (int o = 32; o > 0; o >>= 1) m = fmaxf(m, __shfl_down(m, o));
    if (lane == 0) {
      Mrow[b] = m;
      Sb[b] = fast_exp_d(20.0 * (double)m);
    }
  }
}

// ---------------------------------------------------------------------------
// Init: w_cur = w_in, buf = 0, k2 = softmax(w_in) (f64), zero u0 accumulator.
__global__ __launch_bounds__(256) void kInit(const float* __restrict__ w_in,
                                             float* __restrict__ w_cur,
                                             float* __restrict__ buf,
                                             double* __restrict__ k2,
                                             double* __restrict__ u0z) {
  __shared__ double sred[256];
  int t = threadIdx.x;
  float wv = w_in[t];
  w_cur[t] = wv;
  buf[t] = 0.0f;
  u0z[t] = 0.0;
  double x = (double)wv;
  double m = block_max(x, sred, t);
  double e = fast_exp_d(x - m);
  double s = block_sum(e, sred, t);
  k2[t] = e / s;
}

// ---------------------------------------------------------------------------
// Type-A pass: per-row (over k) weighted reduction. One wave per row.
// WMODE 0: alpha[k] = k2[k]/u[k]
// WMODE 1: alpha[k] = -(g1[k]+g2[k])*k2[k]/u[k]^2
// WMODE 2: alpha[k] = -g1[k]*k2[k]/u[k]^2
// OMODE 0: out_v[b] = s1
// OMODE 1: out_v[b] = s1; out_g[b] = s2/(B*s1^2)   (s2 = sum alpha*E*P)
// OMODE 2: out_g[b] = -s1/(B*vref[b]^2)
// Block 0 additionally zeroes zptr[0:zcnt] (accumulator for the NEXT kB).
template <int WMODE, int OMODE>
__global__ __launch_bounds__(256) void kA(
    const float* __restrict__ feat, const float* __restrict__ Mrow,
    const double* __restrict__ k2, const double* __restrict__ u,
    const double* __restrict__ g1, const double* __restrict__ g2,
    const double* __restrict__ vref, double* __restrict__ out_v,
    double* __restrict__ out_g, double* __restrict__ zptr, int zcnt) {
  __shared__ double alpha[KDIM];
  int t = threadIdx.x;
  if (blockIdx.x == 0) {
    for (int z = t; z < zcnt; z += 256) zptr[z] = 0.0;
  }
  double al;
  if constexpr (WMODE == 0) {
    al = k2[t] / u[t];
  } else if constexpr (WMODE == 1) {
    double uu = u[t];
    al = -(g1[t] + g2[t]) * k2[t] / (uu * uu);
  } else {
    double uu = u[t];
    al = -g1[t] * k2[t] / (uu * uu);
  }
  alpha[t] = al;
  __syncthreads();
  int wv = t >> 6, lane = t & 63;
  double a0 = alpha[lane * 4 + 0], a1 = alpha[lane * 4 + 1];
  double a2 = alpha[lane * 4 + 2], a3 = alpha[lane * 4 + 3];
  int b0 = blockIdx.x * 64;
#pragma unroll 4
  for (int r = wv; r < 64; r += 4) {
    int b = b0 + r;
    float m = Mrow[b];
    float4 f4 = reinterpret_cast<const float4*>(feat + (size_t)b * KDIM)[lane];
    double e0 = (double)exp2f((f4.x - m) * L2E20);
    double e1 = (double)exp2f((f4.y - m) * L2E20);
    double e2 = (double)exp2f((f4.z - m) * L2E20);
    double e3 = (double)exp2f((f4.w - m) * L2E20);
    double s1 = a0 * e0 + a1 * e1 + a2 * e2 + a3 * e3;
    double s2 = 0.0;
    if constexpr (OMODE == 1) {
      s2 = a0 * e0 * (double)f4.x + a1 * e1 * (double)f4.y +
           a2 * e2 * (double)f4.z + a3 * e3 * (double)f4.w;
    }
    s1 = wave_sum(s1);
    if constexpr (OMODE == 1) s2 = wave_sum(s2);
    if (lane == 0) {
      if constexpr (OMODE == 0) {
        out_v[b] = s1;
      } else if constexpr (OMODE == 1) {
        out_v[b] = s1;
        out_g[b] = s2 / (16384.0 * s1 * s1);
      } else {
        double vr = vref[b];
        out_g[b] = -s1 / (16384.0 * vr * vr);
      }
    }
  }
}

// ---------------------------------------------------------------------------
// Type-B pass: per-k reduction over b. Thread t owns column k=t; block covers
// 64 rows; f64 atomic accumulate into out (pre-zeroed by the preceding kA).
// MODE 0: acc += E~ * arr[b]             (u0 with arr=Sb; g-passes with arr=gv)
// MODE 1: acc += E~ / (B*arr[b])         (u-passes, arr = v~)
// MODE 2: acc1 += E~ * P * (-1/(B*arr[b])); acc2 += E~ * arr2[b]   (gdir, t3)
template <int MODE>
__global__ __launch_bounds__(256) void kB(
    const float* __restrict__ feat, const float* __restrict__ Mrow,
    const double* __restrict__ arr, const double* __restrict__ arr2,
    double* __restrict__ out1, double* __restrict__ out2) {
  __shared__ double w1[64];
  __shared__ double w2[64];
  __shared__ float mr[64];
  int t = threadIdx.x;
  int b0 = blockIdx.x * 64;
  if (t < 64) {
    int b = b0 + t;
    mr[t] = Mrow[b];
    if constexpr (MODE == 0) {
      w1[t] = arr[b];
    } else if constexpr (MODE == 1) {
      w1[t] = 1.0 / (16384.0 * arr[b]);
    } else {
      w1[t] = -1.0 / (16384.0 * arr[b]);
      w2[t] = arr2[b];
    }
  }
  __syncthreads();
  double acc1 = 0.0, acc2 = 0.0;
#pragma unroll 8
  for (int r = 0; r < 64; ++r) {
    float f = feat[(size_t)(b0 + r) * KDIM + t];
    double ed = (double)exp2f((f - mr[r]) * L2E20);
    if constexpr (MODE == 2) {
      acc1 += ed * (double)f * w1[r];
      acc2 += ed * w2[r];
    } else {
      acc1 += ed * w1[r];
    }
  }
  unsafeAtomicAdd(&out1[t], acc1);
  if constexpr (MODE == 2) unsafeAtomicAdd(&out2[t], acc2);
}

// ---------------------------------------------------------------------------
// 256-wide optimizer step: softmax-bwd, KL-reg grad, clip, momentum, w update,
// k2 = softmax(w_new) for the next outer iteration.
__global__ __launch_bounds__(256) void kW(
    double* __restrict__ k2, const double* __restrict__ u0,
    const double* __restrict__ u1, const double* __restrict__ u2,
    const double* __restrict__ gdir, const double* __restrict__ t3,
    const double* __restrict__ ga2, const double* __restrict__ ga1,
    float* __restrict__ w, float* __restrict__ buf) {
  __shared__ double sred[256];
  int t = threadIdx.x;
  double k2v = k2[t];
  double ga3 = gdir[t] + t3[t];
  double gk2 = ga3 / u2[t] + ga2[t] / u1[t] + ga1[t] / u0[t];
  double dot = block_sum(k2v * gk2, sred, t);
  // softmax backward + GAMMA * d(reg)/dw  (GAMMA=5, K=256)
  double gw = k2v * (gk2 - dot) + 5.0 * (k2v / 256.0 - 1.0 / 65536.0);
  double n2 = block_sum(gw * gw, sred, t);
  float normf = (float)sqrt(n2);
  float sc = fminf(1.0f, 1.0f / (normf + 1e-6f));
  float g = (float)gw * sc;
  float nb = 0.99f * buf[t] + g;
  buf[t] = nb;
  float nw = w[t] - 0.1f * nb;
  w[t] = nw;
  // k2 = softmax(new w)
  double x = (double)nw;
  double m = block_max(x, sred, t);
  double e = fast_exp_d(x - m);
  double s = block_sum(e, sred, t);
  k2[t] = e / s;
}

// ---------------------------------------------------------------------------
// Output: Q[b,k] = alpha3[k] * E~[k,b] / v3~[b], stored f32.
__global__ __launch_bounds__(256) void kO(const float* __restrict__ feat,
                                          const float* __restrict__ Mrow,
                                          const double* __restrict__ k2,
                                          const double* __restrict__ u2,
                                          const double* __restrict__ v3,
                                          float* __restrict__ out) {
  __shared__ double alpha[KDIM];
  __shared__ double iv3[64];
  __shared__ float mr[64];
  int t = threadIdx.x;
  int b0 = blockIdx.x * 64;
  alpha[t] = k2[t] / u2[t];
  if (t < 64) {
    int b = b0 + t;
    mr[t] = Mrow[b];
    iv3[t] = 1.0 / v3[b];
  }
  __syncthreads();
  double al = alpha[t];
#pragma unroll 4
  for (int r = 0; r < 64; ++r) {
    int b = b0 + r;
    float f = feat[(size_t)b * KDIM + t];
    double ed = (double)exp2f((f - mr[r]) * L2E20);
    out[(size_t)b * KDIM + t] = (float)(al * ed * iv3[r]);
  }
}

// ---------------------------------------------------------------------------
extern "C" void kernel_launch(void* const* d_in, const int* in_sizes, int n_in,
                              void* d_out, int out_size, void* d_ws,
                              size_t ws_size, hipStream_t stream) {
  (void)in_sizes; (void)n_in; (void)out_size; (void)ws_size;
  const float* feat = (const float*)d_in[0];
  const float* w_in = (const float*)d_in[1];
  float* out = (float*)d_out;

  double* ws = (double*)d_ws;
  double* v1  = ws + 0 * BATCH;
  double* v2  = ws + 1 * BATCH;
  double* v3  = ws + 2 * BATCH;
  double* gv3 = ws + 3 * BATCH;
  double* gv2 = ws + 4 * BATCH;
  double* gv1 = ws + 5 * BATCH;
  double* Sb  = ws + 6 * BATCH;
  double* karr = ws + 7 * BATCH;
  double* u0   = karr + 0 * KDIM;
  double* u1   = karr + 1 * KDIM;
  double* u2   = karr + 2 * KDIM;
  double* gdir = karr + 3 * KDIM;  // t3 must be gdir+256 (zeroed together)
  double* t3   = karr + 4 * KDIM;
  double* ga2  = karr + 5 * KDIM;
  double* ga1  = karr + 6 * KDIM;
  double* k2   = karr + 7 * KDIM;
  float* freg  = (float*)(karr + 8 * KDIM);
  float* Mrow  = freg;             // [BATCH]
  float* w_cur = freg + BATCH;     // [256]
  float* buf   = freg + BATCH + KDIM;

  constexpr int G = BATCH / 64;  // 256 blocks, 64 rows each

  kInit<<<1, 256, 0, stream>>>(w_in, w_cur, buf, k2, u0);
  kM<<<G, 256, 0, stream>>>(feat, Mrow, Sb);
  // u0[k] = sum_b E[k,b]  (true scale via Sb)
  kB<0><<<G, 256, 0, stream>>>(feat, Mrow, Sb, nullptr, u0, nullptr);

  for (int it = 0; it < 10; ++it) {
    // v1~ = E~^T (k2/u0); zero u1
    kA<0, 0><<<G, 256, 0, stream>>>(feat, Mrow, k2, u0, nullptr, nullptr,
                                    nullptr, v1, nullptr, u1, KDIM);
    // u1 = sum_b E~/(B v1~)
    kB<1><<<G, 256, 0, stream>>>(feat, Mrow, v1, nullptr, u1, nullptr);
    // v2~ = E~^T (k2/u1); zero u2
    kA<0, 0><<<G, 256, 0, stream>>>(feat, Mrow, k2, u1, nullptr, nullptr,
                                    nullptr, v2, nullptr, u2, KDIM);
    kB<1><<<G, 256, 0, stream>>>(feat, Mrow, v2, nullptr, u2, nullptr);
    if (it < 9) {
      // v3~, gv3~ = S~/(B v3~^2); zero gdir+t3 (contiguous 512)
      kA<0, 1><<<G, 256, 0, stream>>>(feat, Mrow, k2, u2, nullptr, nullptr,
                                      nullptr, v3, gv3, gdir, 2 * KDIM);
      // gdir[k] = -(1/B) sum E~ P / v3~ ;  t3[k] = sum E~ gv3~
      kB<2><<<G, 256, 0, stream>>>(feat, Mrow, v3, gv3, gdir, t3);
      // gv2~ = -(sum_k gu2 E~)/(B v2~^2), gu2 = -(gdir+t3)k2/u2^2; zero ga2
      kA<1, 2><<<G, 256, 0, stream>>>(feat, Mrow, k2, u2, gdir, t3, v2,
                                      nullptr, gv2, ga2, KDIM);
      kB<0><<<G, 256, 0, stream>>>(feat, Mrow, gv2, nullptr, ga2, nullptr);
      // gv1~ = -(sum_k gu1 E~)/(B v1~^2), gu1 = -ga2*k2/u1^2; zero ga1
      kA<2, 2><<<G, 256, 0, stream>>>(feat, Mrow, k2, u1, ga2, nullptr, v1,
                                      nullptr, gv1, ga1, KDIM);
      kB<0><<<G, 256, 0, stream>>>(feat, Mrow, gv1, nullptr, ga1, nullptr);
      // optimizer step + new k2
      kW<<<1, 256, 0, stream>>>(k2, u0, u1, u2, gdir, t3, ga2, ga1, w_cur, buf);
    } else {
      // last iteration: only need v3 and the output Q
      kA<0, 0><<<G, 256, 0, stream>>>(feat, Mrow, k2, u2, nullptr, nullptr,
                                      nullptr, v3, nullptr, nullptr, 0);
      kO<<<G, 256, 0, stream>>>(feat, Mrow, k2, u2, v3, out);
    }
  }
}